// Round 3
// baseline (3990.648 us; speedup 1.0000x reference)
//
#include <hip/hip_runtime.h>
#include <math.h>

typedef unsigned short u16;
typedef __attribute__((ext_vector_type(4))) float f32x4;
typedef __attribute__((ext_vector_type(8))) __bf16 bf16x8;
typedef __attribute__((ext_vector_type(8))) u16 u16x8;
typedef __attribute__((ext_vector_type(4))) u16 u16x4;

#define D_MODEL 4096
#define NQKV    12288
#define BL      2048
#define L_SEQ   1024
#define NH      32
#define DH      128

__device__ __forceinline__ u16 f2bf(float f) {
    union { float f; unsigned u; } v; v.f = f;
    unsigned r = (v.u + 0x7fffu + ((v.u >> 16) & 1u)) >> 16;
    return (u16)r;
}
__device__ __forceinline__ float bf2f(u16 b) {
    union { unsigned u; float f; } v; v.u = ((unsigned)b) << 16;
    return v.f;
}
__device__ __forceinline__ void gload_lds16(const void* g, void* l) {
    __builtin_amdgcn_global_load_lds((const __attribute__((address_space(1))) void*)g,
                                     (__attribute__((address_space(3))) void*)l, 16, 0, 0);
}
__device__ __forceinline__ f32x4 mfma_bf16(bf16x8 a, bf16x8 b, f32x4 c) {
    return __builtin_amdgcn_mfma_f32_16x16x32_bf16(a, b, c, 0, 0, 0);
}

// raw barrier (no implicit vmcnt(0) drain) + compiler memory fence
#define BAR()      asm volatile("s_barrier" ::: "memory")
#define WAIT_VM4() asm volatile("s_waitcnt vmcnt(4)" ::: "memory")
#define WAIT_VM0() asm volatile("s_waitcnt vmcnt(0)" ::: "memory")

// ---------------- fp32 -> bf16 convert (hidden states) ----------------
__global__ __launch_bounds__(256) void convert_f32_bf16(const float* __restrict__ in,
                                                        u16* __restrict__ out, int n4) {
    int i = blockIdx.x * 256 + threadIdx.x;
    if (i < n4) {
        float4 v = ((const float4*)in)[i];
        u16x4 o;
        o[0] = f2bf(v.x); o[1] = f2bf(v.y); o[2] = f2bf(v.z); o[3] = f2bf(v.w);
        ((u16x4*)out)[i] = o;
    }
}

// ---------------- fp32 W[K][N] -> bf16 Wt[N][K], coalesced both sides -----------
// wave w: k-octet kt+w*8; lane l: n = nt+l. 8 coalesced 256B reads -> 1KB/wave write.
__global__ __launch_bounds__(256) void transpose_convert(const float* __restrict__ W,
                                                         u16* __restrict__ Wt, int K, int N) {
    const int l = threadIdx.x & 63, w = threadIdx.x >> 6;
    const int nt = blockIdx.x * 64, kt = blockIdx.y * 32 + w * 8;
    const int n = nt + l;
    u16x8 o;
#pragma unroll
    for (int j = 0; j < 8; ++j)
        o[j] = f2bf(W[(size_t)(kt + j) * N + n]);
    *(u16x8*)&Wt[(size_t)n * K + kt] = o;
}

// ---------------- vmask + expert row lists (deterministic scan) ----------------
__global__ __launch_bounds__(256) void mask_scan(const int* __restrict__ tt,
                                                 int* __restrict__ lists,
                                                 int* __restrict__ counts) {
    __shared__ int buf[256];
    int tid = threadIdx.x;
    int base = tid * 8;
    int flags = 0, cv = 0;
#pragma unroll
    for (int j = 0; j < 8; ++j) {
        int i = base + j;
        int l = i & (L_SEQ - 1);
        int f = (l < L_SEQ - 1) && (tt[i] == 1) && (tt[i + 1] == 1);
        flags |= f << j; cv += f;
    }
    buf[tid] = cv; __syncthreads();
    for (int d = 1; d < 256; d <<= 1) {
        int t = (tid >= d) ? buf[tid - d] : 0;
        __syncthreads();
        buf[tid] += t;
        __syncthreads();
    }
    int vs = buf[tid] - cv;     // exclusive vis prefix
    int ls = base - vs;         // exclusive lang prefix
    int total_v = buf[255];
#pragma unroll
    for (int j = 0; j < 8; ++j) {
        int i = base + j;
        if ((flags >> j) & 1) lists[vs++] = i;
        else                  lists[2048 + ls++] = i;
    }
    if (tid == 0) { counts[0] = total_v; counts[1] = 2048 - total_v; }
}

// ---------------- 256x256 bf16 GEMM, ring-5 LDS (80KB -> 2 blocks/CU) -----------
// 512 threads = 8 waves (2M x 4N), per-wave 128x64, BK=64 split in two 16KB K-half
// units per matrix: unit u = 4t+j, j in {A-k0, B-k0, A-k1, B-k1}; slot = u % 5.
// Per phase: [ds_reads; BAR; MFMA; BAR; STAGE(u=P+4)]; guards (vmcnt(4)+BAR) after
// phases 1 and 3 only. Slot reuse distance 5 units: unit P-1's last reads complete
// before the post-MFMA BAR of phase P, so staging after that BAR is race-free.
template <typename OutT>
__global__ __launch_bounds__(512, 4) void gemm_expert(
    const u16* __restrict__ A, const u16* __restrict__ BtVis, const u16* __restrict__ BtLang,
    OutT* __restrict__ C, const int* __restrict__ lists, const int* __restrict__ counts, int ldc) {
    const int e = blockIdx.z;
    const int cnt = counts[e];
    const int m0 = blockIdx.y * 256;
    if (m0 >= cnt) return;
    const u16* Bt = (e == 0) ? BtVis : BtLang;
    const int* list = lists + e * 2048;
    const int n0 = blockIdx.x * 256;
    const int tid = threadIdx.x, lane = tid & 63, w = tid >> 6;
    const int wm = w >> 2, wn = w & 3;          // 2 x 4 wave grid
    const int l16 = lane & 15, quad = lane >> 4;

    __shared__ __align__(16) u16 ring[5][8192];  // 5 x 16KB units

    const int r0 = tid >> 2;                    // 0..127
    const int cs = (tid & 3) ^ ((r0 >> 1) & 3); // swizzled source chunk (same for both j)
    const char* pa0 = (const char*)(A + (size_t)list[min(m0 + r0, cnt - 1)] * D_MODEL) + cs * 16;
    const char* pa1 = (const char*)(A + (size_t)list[min(m0 + 128 + r0, cnt - 1)] * D_MODEL) + cs * 16;
    const char* pb0 = (const char*)(Bt + (size_t)(n0 + r0) * D_MODEL) + cs * 16;
    const char* pb1 = (const char*)(Bt + (size_t)(n0 + 128 + r0) * D_MODEL) + cs * 16;
    const int dst0 = w * 512;                   // u16 index, wave-uniform
    const int dst1 = 4096 + w * 512;

    auto STAGE = [&](int slot, int u4, int tk) {
        const int kbyte = tk * 128 + ((u4 & 2) ? 64 : 0);
        const char* g0 = (u4 & 1) ? pb0 : pa0;
        const char* g1 = (u4 & 1) ? pb1 : pa1;
        u16* d = &ring[slot][0];
        gload_lds16(g0 + kbyte, d + dst0);
        gload_lds16(g1 + kbyte, d + dst1);
    };

    f32x4 acc[8][4] = {};
    const int NT = D_MODEL / 64;                // 64 K-tiles, 256 units

    // ---- prologue: stage units 0..3 (tile 0); guard units 0,1 ----
    STAGE(0, 0, 0); STAGE(1, 1, 0); STAGE(2, 2, 0); STAGE(3, 3, 0);
    WAIT_VM4();
    BAR();

    int sA = 0;          // slot of unit 4t
    int ss = 4;          // slot for next staged unit
    int us = 4;          // next unit index to stage

    for (int t = 0; t < NT; ++t) {
        const int s0 = sA, s1 = (sA + 1) % 5, s2 = (sA + 2) % 5, s3 = (sA + 3) % 5;
        bf16x8 af[4], bf[4];

        // ===== phase 0: A-k0 m-half0 (s0) x B-k0 (s1) =====
#pragma unroll
        for (int ni = 0; ni < 4; ++ni) {
            int row = wn * 64 + ni * 16 + l16;
            bf[ni] = *(const bf16x8*)&ring[s1][row * 32 + (quad ^ ((row >> 1) & 3)) * 8];
        }
#pragma unroll
        for (int mi = 0; mi < 4; ++mi) {
            int row = wm * 128 + mi * 16 + l16;
            af[mi] = *(const bf16x8*)&ring[s0][row * 32 + (quad ^ ((row >> 1) & 3)) * 8];
        }
        BAR();
        __builtin_amdgcn_s_setprio(1);
#pragma unroll
        for (int mi = 0; mi < 4; ++mi)
#pragma unroll
            for (int ni = 0; ni < 4; ++ni)
                acc[mi][ni] = mfma_bf16(af[mi], bf[ni], acc[mi][ni]);
        __builtin_amdgcn_s_setprio(0);
        BAR();
        if (us < 4 * NT) { STAGE(ss, us & 3, us >> 2); ss = (ss + 1) % 5; ++us; }

        // ===== phase 1: A-k0 m-half1 (s0), reuse bf =====
#pragma unroll
        for (int mi = 0; mi < 4; ++mi) {
            int row = wm * 128 + 64 + mi * 16 + l16;
            af[mi] = *(const bf16x8*)&ring[s0][row * 32 + (quad ^ ((row >> 1) & 3)) * 8];
        }
        BAR();
        __builtin_amdgcn_s_setprio(1);
#pragma unroll
        for (int mi = 0; mi < 4; ++mi)
#pragma unroll
            for (int ni = 0; ni < 4; ++ni)
                acc[4 + mi][ni] = mfma_bf16(af[mi], bf[ni], acc[4 + mi][ni]);
        __builtin_amdgcn_s_setprio(0);
        BAR();
        if (us < 4 * NT) { STAGE(ss, us & 3, us >> 2); ss = (ss + 1) % 5; ++us; }
        // guard phase-2 reads: A-k1(t), B-k1(t) landed in every wave
        if (t == NT - 1) WAIT_VM0(); else WAIT_VM4();
        BAR();

        // ===== phase 2: A-k1 m-half0 (s2) x B-k1 (s3) =====
#pragma unroll
        for (int ni = 0; ni < 4; ++ni) {
            int row = wn * 64 + ni * 16 + l16;
            bf[ni] = *(const bf16x8*)&ring[s3][row * 32 + (quad ^ ((row >> 1) & 3)) * 8];
        }
#pragma unroll
        for (int mi = 0; mi < 4; ++mi) {
            int row = wm * 128 + mi * 16 + l16;
            af[mi] = *(const bf16x8*)&ring[s2][row * 32 + (quad ^ ((row >> 1) & 3)) * 8];
        }
        BAR();
        __builtin_amdgcn_s_setprio(1);
#pragma unroll
        for (int mi = 0; mi < 4; ++mi)
#pragma unroll
            for (int ni = 0; ni < 4; ++ni)
                acc[mi][ni] = mfma_bf16(af[mi], bf[ni], acc[mi][ni]);
        __builtin_amdgcn_s_setprio(0);
        BAR();
        if (us < 4 * NT) { STAGE(ss, us & 3, us >> 2); ss = (ss + 1) % 5; ++us; }

        // ===== phase 3: A-k1 m-half1 (s2), reuse bf =====
#pragma unroll
        for (int mi = 0; mi < 4; ++mi) {
            int row = wm * 128 + 64 + mi * 16 + l16;
            af[mi] = *(const bf16x8*)&ring[s2][row * 32 + (quad ^ ((row >> 1) & 3)) * 8];
        }
        BAR();
        __builtin_amdgcn_s_setprio(1);
#pragma unroll
        for (int mi = 0; mi < 4; ++mi)
#pragma unroll
            for (int ni = 0; ni < 4; ++ni)
                acc[4 + mi][ni] = mfma_bf16(af[mi], bf[ni], acc[4 + mi][ni]);
        __builtin_amdgcn_s_setprio(0);
        BAR();
        if (us < 4 * NT) { STAGE(ss, us & 3, us >> 2); ss = (ss + 1) % 5; ++us; }
        // guard next tile's phase-0 reads: A-k0(t+1), B-k0(t+1)
        if (t + 1 < NT) { WAIT_VM4(); BAR(); }

        sA = (sA + 4) % 5;
    }

    // ---- epilogue: per-wave 128x64 at (wm*128, wn*64)
#pragma unroll
    for (int mf = 0; mf < 8; ++mf) {
#pragma unroll
        for (int r = 0; r < 4; ++r) {
            int slot = m0 + wm * 128 + mf * 16 + quad * 4 + r;
            if (slot < cnt) {
                int row = list[slot];
                size_t rb = (size_t)row * ldc + n0 + wn * 64 + l16;
#pragma unroll
                for (int ni = 0; ni < 4; ++ni) {
                    float v = acc[mf][ni][r];
                    if constexpr (sizeof(OutT) == 2) C[rb + ni * 16] = (OutT)f2bf(v);
                    else                             C[rb + ni * 16] = v;
                }
            }
        }
    }
}

// ---------------- RoPE in-place on q,k halves of QKV (bf16) ----------------
__global__ __launch_bounds__(256) void rope_kernel(u16* __restrict__ qkv,
                                                   const int* __restrict__ posi) {
    int idx = blockIdx.x * 256 + threadIdx.x;    // [0, 2048*32*64)
    int t = idx >> 11;
    int rem = idx & 2047;
    int h = rem >> 6;
    int j = rem & 63;
    int l = t & (L_SEQ - 1);
    int is_i32 = posi[1];                          // 1 => int32 layout, 0 => int64 layout
    int pv = is_i32 ? posi[l] : posi[2 * l];       // int64 low word (positions < 2^31)
    float p = (float)pv;
    float inv = __expf(-(float)j * 0.14391156831212787f);  // ln(10000)/64
    float ang = p * inv;
    float s, c;
    __sincosf(ang, &s, &c);
    size_t base = (size_t)t * NQKV + h * DH + j;
    float x1 = bf2f(qkv[base]), x2 = bf2f(qkv[base + 64]);
    qkv[base]      = f2bf(x1 * c - x2 * s);
    qkv[base + 64] = f2bf(x2 * c + x1 * s);
    size_t kb = base + D_MODEL;
    x1 = bf2f(qkv[kb]); x2 = bf2f(qkv[kb + 64]);
    qkv[kb]      = f2bf(x1 * c - x2 * s);
    qkv[kb + 64] = f2bf(x2 * c + x1 * s);
}

// ---------------- flash attention (causal), KVBLK=64, pipelined, swizzled LDS ------
__global__ __launch_bounds__(256, 2) void attn_kernel(const u16* __restrict__ qkv,
                                                      u16* __restrict__ ctx) {
    const int qt = (int)gridDim.x - 1 - (int)blockIdx.x;   // longest blocks first
    const int h = blockIdx.y, b = blockIdx.z;
    const int tid = threadIdx.x, lane = tid & 63, w = tid >> 6;
    const int quad = lane >> 4, l16 = lane & 15;

    __shared__ __align__(16) u16 Ks[2][64 * 128];
    __shared__ __align__(16) u16 Vt[2][128 * 64];
    __shared__ __align__(16) u16 Ps[4][16 * 64];

    // --- Q fragments directly into registers (A-frag row = l16 -> q = w*16+l16) ---
    const size_t qbase = ((size_t)(b * L_SEQ + qt * 64 + w * 16 + l16)) * NQKV + h * DH;
    bf16x8 aq[4];
#pragma unroll
    for (int kc = 0; kc < 4; ++kc)
        aq[kc] = *(const bf16x8*)&qkv[qbase + kc * 32 + quad * 8];

    // staging coords: thread covers 4 (row, chunk) pairs of the 64x128 K/V tile
    int srow[4], schk[4];
#pragma unroll
    for (int i = 0; i < 4; ++i) {
        int idx = i * 256 + tid;
        srow[i] = idx >> 4;
        schk[i] = idx & 15;
    }
    const size_t kv0 = ((size_t)(b * L_SEQ)) * NQKV + D_MODEL + h * DH;

    float m_i[4], l_i[4];
    f32x4 o[8] = {};
#pragma unroll
    for (int r = 0; r < 4; ++r) { m_i[r] = -1e30f; l_i[r] = 0.f; }
    const float scale = 0.08838834764831845f;  // 1/sqrt(128)
    const int jmax = qt + 1;

    // ---- prologue: stage tile 0 into buf 0 ----
    {
        u16x8 kr[4], vr[4];
#pragma unroll
        for (int i = 0; i < 4; ++i) {
            size_t g = kv0 + (size_t)srow[i] * NQKV + schk[i] * 8;
            kr[i] = *(const u16x8*)&qkv[g];
            vr[i] = *(const u16x8*)&qkv[g + D_MODEL];
        }
#pragma unroll
        for (int i = 0; i < 4; ++i) {
            int r = srow[i], c = schk[i];
            *(u16x8*)&Ks[0][r * 128 + ((c ^ (r & 7)) * 8)] = kr[i];
#pragma unroll
            for (int e = 0; e < 8; ++e) {
                int d = c * 8 + e;
                int sw = (r >> 3) ^ ((d ^ (d >> 3)) & 7);
                Vt[0][d * 64 + sw * 8 + (r & 7)] = vr[i][e];
            }
        }
    }
    __syncthreads();

    for (int jt = 0; jt < jmax; ++jt) {
        const int cur = jt & 1;
        const bool pf = (jt + 1 < jmax);

        // ---- issue next tile's global loads (latency hides under compute) ----
        u16x8 kr[4], vr[4];
        if (pf) {
            const size_t kb = kv0 + (size_t)((jt + 1) * 64) * NQKV;
#pragma unroll
            for (int i = 0; i < 4; ++i) {
                size_t g = kb + (size_t)srow[i] * NQKV + schk[i] * 8;
                kr[i] = *(const u16x8*)&qkv[g];
                vr[i] = *(const u16x8*)&qkv[g + D_MODEL];
            }
        }

        // ---- QK^T: 4 key-subtiles x 4 k-chunks ----
        f32x4 s[4] = {};
        __builtin_amdgcn_s_setprio(1);
#pragma unroll
        for (int sub = 0; sub < 4; ++sub) {
            const int row = sub * 16 + l16;
#pragma unroll
            for (int kc = 0; kc < 4; ++kc) {
                bf16x8 bk = *(const bf16x8*)&Ks[cur][row * 128 + (((kc * 4 + quad) ^ (row & 7)) * 8)];
                s[sub] = mfma_bf16(aq[kc], bk, s[sub]);
            }
        }
        __builtin_amdgcn_s_setprio(0);

        // ---- masked online softmax (rows = q = quad*4+r, cols = key = sub*16+l16) ----
        const int qg = qt * 64 + w * 16 + quad * 4;
        float p[4][4], mx[4];
#pragma unroll
        for (int r = 0; r < 4; ++r) mx[r] = -1e30f;
#pragma unroll
        for (int sub = 0; sub < 4; ++sub) {
            const int kg = jt * 64 + sub * 16 + l16;
#pragma unroll
            for (int r = 0; r < 4; ++r) {
                float sv = (kg <= qg + r) ? s[sub][r] * scale : -1e30f;
                p[sub][r] = sv;
                mx[r] = fmaxf(mx[r], sv);
            }
        }
#pragma unroll
        for (int d = 1; d < 16; d <<= 1)
#pragma unroll
            for (int r = 0; r < 4; ++r) mx[r] = fmaxf(mx[r], __shfl_xor(mx[r], d));
        float alpha[4], rs[4];
#pragma unroll
        for (int r = 0; r < 4; ++r) {
            float mn = fmaxf(m_i[r], mx[r]);
            alpha[r] = __expf(m_i[r] - mn);
            m_i[r] = mn;
            rs[r] = 0.f;
        }
#pragma unroll
        for (int sub = 0; sub < 4; ++sub)
#pragma unroll
            for (int r = 0; r < 4; ++r) {
                p[sub][r] = __expf(p[sub][r] - m_i[r]);
                rs[r] += p[sub][r];
            }
#pragma unroll
        for (int d = 1; d < 16; d <<= 1)
#pragma unroll
            for (int r = 0; r < 4; ++r) rs[r] += __shfl_xor(rs[r], d);

        // ---- P -> per-warp LDS (C-layout -> A-layout); no barrier needed ----
#pragma unroll
        for (int sub = 0; sub < 4; ++sub)
#pragma unroll
            for (int r = 0; r < 4; ++r) {
                const int q = quad * 4 + r;
                const int chunk = sub * 2 + (l16 >> 3);
                Ps[w][q * 64 + ((chunk ^ (q & 7)) * 8) + (l16 & 7)] = f2bf(p[sub][r]);
            }
#pragma unroll
        for (int r = 0; r < 4; ++r) l_i[r] = l_i[r] * alpha[r] + rs[r];
#pragma unroll
        for (int n = 0; n < 8; ++n)
#pragma unroll
            for (int r = 0; r < 4; ++r) o[n][r] *= alpha[r];

        // ---- PV: 2 k-halves x 8 d-chunks ----
        __builtin_amdgcn_s_setprio(1);
#pragma unroll
        for (int ks = 0; ks < 2; ++ks) {
            bf16x8 ap = *(const bf16x8*)&Ps[w][l16 * 64 + (((ks * 4 + quad) ^ (l16 & 7)) * 8)];
#pragma unroll
            for (int n = 0; n < 8; ++n) {
                const int d = n * 16 + l16;
                bf16x8 bv = *(const bf16x8*)&Vt[cur][d * 64 + (((ks * 4 + quad) ^ ((d ^ (d >> 3)) & 7)) * 8)];
                o[n] = mfma_bf16(ap, bv, o[n]);
            }
        }
        __builtin_amdgcn_s_setprio(0);

        // ---- write prefetched tile into the other buffer, single barrier ----
        if (pf) {
            const int nb = cur ^ 1;
#pragma unroll
            for (int i = 0; i < 4; ++i) {
                int r = srow[i], c = schk[i];
                *(u16x8*)&Ks[nb][r * 128 + ((c ^ (r & 7)) * 8)] = kr[i];
#pragma unroll
                for (int e = 0; e < 8; ++e) {
                    int d = c * 8 + e;
                    int sw = (r >> 3) ^ ((d ^ (d >> 3)) & 7);
                    Vt[nb][d * 64 + sw * 8 + (r & 7)] = vr[i][e];
                }
            }
        }
        __syncthreads();
    }

    const int tglob = b * L_SEQ + qt * 64 + w * 16 + quad * 4;
#pragma unroll
    for (int r = 0; r < 4; ++r) {
        float invl = 1.f / l_i[r];
#pragma unroll
        for (int n = 0; n < 8; ++n)
            ctx[(size_t)(tglob + r) * D_MODEL + h * DH + n * 16 + l16] = f2bf(o[n][r] * invl);
    }
}

extern "C" void kernel_launch(void* const* d_in, const int* in_sizes, int n_in,
                              void* d_out, int out_size, void* d_ws, size_t ws_size,
                              hipStream_t stream) {
    const float* hidden = (const float*)d_in[0];
    const int* tt = (const int*)d_in[1];
    const int* pos = (const int*)d_in[2];
    const float* wqv = (const float*)d_in[3];
    const float* wql = (const float*)d_in[4];
    const float* wdv = (const float*)d_in[5];
    const float* wdl = (const float*)d_in[6];
    float* out = (float*)d_out;

    char* ws = (char*)d_ws;
    size_t off = 0;
    auto alloc = [&](size_t bytes) {
        char* p = ws + off;
        off += (bytes + 255) & ~(size_t)255;
        return p;
    };
    u16* WqvT = (u16*)alloc((size_t)NQKV * D_MODEL * 2);
    u16* WqlT = (u16*)alloc((size_t)NQKV * D_MODEL * 2);
    u16* WdvT = (u16*)alloc((size_t)D_MODEL * D_MODEL * 2);
    u16* WdlT = (u16*)alloc((size_t)D_MODEL * D_MODEL * 2);
    u16* Abf  = (u16*)alloc((size_t)BL * D_MODEL * 2);
    u16* QKV  = (u16*)alloc((size_t)BL * NQKV * 2);
    u16* CTX  = (u16*)alloc((size_t)BL * D_MODEL * 2);
    int* lists  = (int*)alloc(4096 * sizeof(int));
    int* counts = (int*)alloc(256);

    convert_f32_bf16<<<BL * D_MODEL / 4 / 256, 256, 0, stream>>>(hidden, Abf, BL * D_MODEL / 4);
    transpose_convert<<<dim3(NQKV / 64, D_MODEL / 32), 256, 0, stream>>>(wqv, WqvT, D_MODEL, NQKV);
    transpose_convert<<<dim3(NQKV / 64, D_MODEL / 32), 256, 0, stream>>>(wql, WqlT, D_MODEL, NQKV);
    transpose_convert<<<dim3(D_MODEL / 64, D_MODEL / 32), 256, 0, stream>>>(wdv, WdvT, D_MODEL, D_MODEL);
    transpose_convert<<<dim3(D_MODEL / 64, D_MODEL / 32), 256, 0, stream>>>(wdl, WdlT, D_MODEL, D_MODEL);
    mask_scan<<<1, 256, 0, stream>>>(tt, lists, counts);
    gemm_expert<u16><<<dim3(NQKV / 256, 8, 2), 512, 0, stream>>>(Abf, WqvT, WqlT, QKV, lists, counts, NQKV);
    rope_kernel<<<BL * NH * 64 / 256, 256, 0, stream>>>(QKV, pos);
    attn_kernel<<<dim3(16, NH, 2), 256, 0, stream>>>(QKV, CTX);
    gemm_expert<float><<<dim3(D_MODEL / 256, 8, 2), 512, 0, stream>>>(CTX, WdvT, WdlT, out, lists, counts, D_MODEL);
}